// Round 4
// baseline (469.156 us; speedup 1.0000x reference)
//
#include <hip/hip_runtime.h>
#include <math.h>

#define DATA 64
#define WIDTH 256
#define BATCHN 512
#define TPTS 16
#define MAXSUB 8
#define NSAMP 2
#define NBLK (BATCHN / NSAMP)
#define NTHR 1024

#define RTOLc 1e-3f
#define ATOLc 1e-6f
#define SAFETYc 0.9f
#define FMINc 0.2f
#define FMAXc 10.0f

// Tsit5 tableau
#define A21 0.161f
#define A31 (-0.008480655492356989f)
#define A32 0.335480655492357f
#define A41 2.8971530571054935f
#define A42 (-6.359448489975075f)
#define A43 4.3622954328695815f
#define A51 5.325864828439257f
#define A52 (-11.748883564062828f)
#define A53 7.4955393428898365f
#define A54 (-0.09249506636175525f)
#define A61 5.86145544294642f
#define A62 (-12.92096931784711f)
#define A63 8.159367898576159f
#define A64 (-0.071584973281401f)
#define A65 (-0.028269050394068383f)
#define B1c 0.09646076681806523f
#define B2c 0.01f
#define B3c 0.4798896504144996f
#define B4c 1.379008574103742f
#define B5c (-3.290069515436081f)
#define B6c 2.324710524099774f
#define E1c (-0.001780011052226f)
#define E2c (-0.000816434459657f)
#define E3c 0.007880878010262f
#define E4c (-0.144711007173263f)
#define E5c 0.582357165452555f
#define E6c (-0.458082105929187f)
#define E7c 0.015151515151515152f

__device__ __forceinline__ float softplus_jax(float x) {
    // jax.nn.softplus(x) == max(x,0) + log1p(exp(-|x|))
    return fmaxf(x, 0.0f) + log1pf(expf(-fabsf(x)));
}

#define DOT4(acc, wq, xv)                                                     \
    acc = fmaf((wq).x, (xv).x, acc); acc = fmaf((wq).y, (xv).y, acc);         \
    acc = fmaf((wq).z, (xv).z, acc); acc = fmaf((wq).w, (xv).w, acc);

// One MLP eval for BOTH samples.
// Roles: (r = t&255, h = t>>8 in 0..3) for layers 0/1 (4-way split-k);
//        (d = t&63, kc = t>>6 in 0..15) for layer 2 (16-way split-k).
// W0^T, W2^T in LDS (lane-consecutive reads); W1 4-way-split in VGPRs (w1q).
// Activation reads are wave-uniform (broadcast). Ends with partials in s_ps2.
#define FEVAL_CORE(PIN0, PIN1)                                                \
    {   /* layer 0 */                                                         \
        const float* x0 = (PIN0) + h * 16;                                    \
        const float* x1 = (PIN1) + h * 16;                                    \
        float a0 = 0.f, a1 = 0.f;                                             \
        _Pragma("unroll")                                                     \
        for (int kk = 0; kk < 16; ++kk) {                                     \
            const float w = sW0T[h * 16 + kk][r];                             \
            a0 = fmaf(w, x0[kk], a0); a1 = fmaf(w, x1[kk], a1);               \
        }                                                                     \
        s_ps[0][h][r] = a0; s_ps[1][h][r] = a1;                               \
    }                                                                         \
    __syncthreads();                                                          \
    if (t < 512) {                                                            \
        const int s = t >> 8;                                                 \
        s_h0[s][r] = softplus_jax(((s_ps[s][0][r] + s_ps[s][1][r])            \
                                 + (s_ps[s][2][r] + s_ps[s][3][r])) + b0r);   \
    }                                                                         \
    __syncthreads();                                                          \
    {   /* layer 1 */                                                         \
        const float4* x0 = reinterpret_cast<const float4*>(&s_h0[0][h * 64]); \
        const float4* x1 = reinterpret_cast<const float4*>(&s_h0[1][h * 64]); \
        float a0 = 0.f, a1 = 0.f, c0 = 0.f, c1 = 0.f;                         \
        _Pragma("unroll")                                                     \
        for (int j = 0; j < 16; j += 2) {                                     \
            float4 u = x0[j], v = x1[j];                                      \
            DOT4(a0, w1q[j], u); DOT4(a1, w1q[j], v);                         \
            float4 u2 = x0[j + 1], v2 = x1[j + 1];                            \
            DOT4(c0, w1q[j + 1], u2); DOT4(c1, w1q[j + 1], v2);               \
        }                                                                     \
        s_ps[0][h][r] = a0 + c0; s_ps[1][h][r] = a1 + c1;                     \
    }                                                                         \
    __syncthreads();                                                          \
    if (t < 512) {                                                            \
        const int s = t >> 8;                                                 \
        s_h1[s][r] = softplus_jax(((s_ps[s][0][r] + s_ps[s][1][r])            \
                                 + (s_ps[s][2][r] + s_ps[s][3][r])) + b1r);   \
    }                                                                         \
    __syncthreads();                                                          \
    {   /* layer 2 */                                                         \
        const float* x0 = &s_h1[0][kc * 16];                                  \
        const float* x1 = &s_h1[1][kc * 16];                                  \
        float a0 = 0.f, a1 = 0.f;                                             \
        _Pragma("unroll")                                                     \
        for (int kk = 0; kk < 16; ++kk) {                                     \
            const float w = sW2T[kc * 16 + kk][d];                            \
            a0 = fmaf(w, x0[kk], a0); a1 = fmaf(w, x1[kk], a1);               \
        }                                                                     \
        s_ps2[0][kc][d] = a0; s_ps2[1][kc][d] = a1;                           \
    }                                                                         \
    __syncthreads();

#define KV_SUM(s)                                                             \
    (((((s_ps2[s][0][d] + s_ps2[s][1][d]) + (s_ps2[s][2][d] + s_ps2[s][3][d]))  \
     + ((s_ps2[s][4][d] + s_ps2[s][5][d]) + (s_ps2[s][6][d] + s_ps2[s][7][d]))) \
    + (((s_ps2[s][8][d] + s_ps2[s][9][d]) + (s_ps2[s][10][d] + s_ps2[s][11][d]))\
     + ((s_ps2[s][12][d] + s_ps2[s][13][d]) + (s_ps2[s][14][d] + s_ps2[s][15][d])))) \
    + b2d)

__global__ __launch_bounds__(NTHR)
void ode_kernel(const float* __restrict__ ts, const float* __restrict__ y0,
                const float* __restrict__ W0, const float* __restrict__ b0,
                const float* __restrict__ W1, const float* __restrict__ b1,
                const float* __restrict__ W2, const float* __restrict__ b2,
                float* __restrict__ out)
{
    __shared__ __align__(16) float sW0T[DATA][WIDTH];    // 64 KB, [k][r]
    __shared__ __align__(16) float sW2T[WIDTH][DATA];    // 64 KB, [k][d]
    __shared__ __align__(16) float s_ps[NSAMP][4][WIDTH];   // 8 KB (layers 0/1)
    __shared__ __align__(16) float s_ps2[NSAMP][16][DATA];  // 8 KB (layer 2)
    __shared__ __align__(16) float s_h0[NSAMP][WIDTH];
    __shared__ __align__(16) float s_h1[NSAMP][WIDTH];
    __shared__ __align__(16) float s_y[NSAMP][DATA];
    __shared__ __align__(16) float s_yst[NSAMP][DATA];
    __shared__ __align__(16) float s_ynew[NSAMP][DATA];
    __shared__ __align__(16) float s_k[NSAMP][6][DATA];
    __shared__ float s_err[NSAMP];

    const int t  = threadIdx.x;
    const int r  = t & 255;
    const int h  = t >> 8;   // 0..3: k-quarter for layers 0/1
    const int d  = t & 63;
    const int kc = t >> 6;   // 0..15: k-chunk for layer 2
    const int b  = blockIdx.x;

    // ---- prologue (one-time): W1 quarter-rows to VGPRs; W0^T, W2^T to LDS
    float4 w1q[16];
    {
        const float4* p1 = reinterpret_cast<const float4*>(W1 + r * WIDTH + h * 64);
#pragma unroll
        for (int j = 0; j < 16; ++j) w1q[j] = p1[j];
    }
    for (int i = t; i < DATA * WIDTH; i += NTHR) {  // coalesced read, transposed LDS write
        const int rr = i >> 6, kk = i & 63;
        sW0T[kk][rr] = W0[i];                        // W0[rr][kk]
    }
    for (int i = t; i < DATA * WIDTH; i += NTHR) {
        const int dd = i >> 8, kk = i & 255;
        sW2T[kk][dd] = W2[i];                        // W2[dd][kk]
    }
    const float b0r = b0[r];
    const float b1r = b1[r];
    const float b2d = b2[d];
    if (t < NSAMP * DATA) {
        const int s = t >> 6;
        const float v = y0[(b * NSAMP + s) * DATA + d];
        s_y[s][d] = v;
        out[(size_t)(b * NSAMP + s) * TPTS * DATA + d] = v;
    }
    __syncthreads();

    // per-sample control state, replicated identically in every thread
    float dtv0 = ts[1] - ts[0];
    float dtv1 = dtv0;

    for (int iv = 0; iv < TPTS - 1; ++iv) {
        const float t1v = ts[iv + 1];
        float tc0 = ts[iv], tc1 = tc0;

        for (int ss = 0; ss < MAXSUB; ++ss) {
            const float rem0 = t1v - tc0, rem1 = t1v - tc1;
            const bool done0 = rem0 <= 1e-6f, done1 = rem1 <= 1e-6f;
            if (done0 && done1) break;  // remaining reference iters are exact identities
            const float dtc0 = done0 ? dtv0 : fminf(dtv0, rem0);
            const float dtc1 = done1 ? dtv1 : fminf(dtv1, rem1);

            // ---- stage 1
            FEVAL_CORE(&s_y[0][0], &s_y[1][0])
            if (t < 128) {
                const int s = t >> 6;
                const float dtc_s = (s == 0) ? dtc0 : dtc1;
                const float kv = KV_SUM(s);
                s_k[s][0][d] = kv;
                s_yst[s][d] = s_y[s][d] + dtc_s * (A21 * kv);
            }
            __syncthreads();
            // ---- stage 2
            FEVAL_CORE(&s_yst[0][0], &s_yst[1][0])
            if (t < 128) {
                const int s = t >> 6;
                const float dtc_s = (s == 0) ? dtc0 : dtc1;
                const float kv = KV_SUM(s);
                s_k[s][1][d] = kv;
                s_yst[s][d] = s_y[s][d] + dtc_s * (A31 * s_k[s][0][d] + A32 * kv);
            }
            __syncthreads();
            // ---- stage 3
            FEVAL_CORE(&s_yst[0][0], &s_yst[1][0])
            if (t < 128) {
                const int s = t >> 6;
                const float dtc_s = (s == 0) ? dtc0 : dtc1;
                const float kv = KV_SUM(s);
                s_k[s][2][d] = kv;
                s_yst[s][d] = s_y[s][d] + dtc_s * (A41 * s_k[s][0][d] + A42 * s_k[s][1][d] + A43 * kv);
            }
            __syncthreads();
            // ---- stage 4
            FEVAL_CORE(&s_yst[0][0], &s_yst[1][0])
            if (t < 128) {
                const int s = t >> 6;
                const float dtc_s = (s == 0) ? dtc0 : dtc1;
                const float kv = KV_SUM(s);
                s_k[s][3][d] = kv;
                s_yst[s][d] = s_y[s][d] + dtc_s * (A51 * s_k[s][0][d] + A52 * s_k[s][1][d]
                                                 + A53 * s_k[s][2][d] + A54 * kv);
            }
            __syncthreads();
            // ---- stage 5
            FEVAL_CORE(&s_yst[0][0], &s_yst[1][0])
            if (t < 128) {
                const int s = t >> 6;
                const float dtc_s = (s == 0) ? dtc0 : dtc1;
                const float kv = KV_SUM(s);
                s_k[s][4][d] = kv;
                s_yst[s][d] = s_y[s][d] + dtc_s * (A61 * s_k[s][0][d] + A62 * s_k[s][1][d]
                                                 + A63 * s_k[s][2][d] + A64 * s_k[s][3][d] + A65 * kv);
            }
            __syncthreads();
            // ---- stage 6 -> y_new
            FEVAL_CORE(&s_yst[0][0], &s_yst[1][0])
            if (t < 128) {
                const int s = t >> 6;
                const float dtc_s = (s == 0) ? dtc0 : dtc1;
                const float kv = KV_SUM(s);
                s_k[s][5][d] = kv;
                s_ynew[s][d] = s_y[s][d] + dtc_s * (B1c * s_k[s][0][d] + B2c * s_k[s][1][d]
                                                  + B3c * s_k[s][2][d] + B4c * s_k[s][3][d]
                                                  + B5c * s_k[s][4][d] + B6c * kv);
            }
            __syncthreads();
            // ---- stage 7 (error estimate only)
            FEVAL_CORE(&s_ynew[0][0], &s_ynew[1][0])
            if (t < 128) {
                const int s = t >> 6;
                const float dtc_s = (s == 0) ? dtc0 : dtc1;
                const float kv = KV_SUM(s);  // k7
                const float e = dtc_s * (E1c * s_k[s][0][d] + E2c * s_k[s][1][d]
                                       + E3c * s_k[s][2][d] + E4c * s_k[s][3][d]
                                       + E5c * s_k[s][4][d] + E6c * s_k[s][5][d] + E7c * kv);
                const float yv = s_y[s][d], ynv = s_ynew[s][d];
                const float sc = ATOLc + RTOLc * fmaxf(fabsf(yv), fabsf(ynv));
                const float rr2 = e / sc;
                float v = rr2 * rr2;
#pragma unroll
                for (int off = 32; off > 0; off >>= 1) v += __shfl_xor(v, off, 64);
                if (d == 0) s_err[s] = v;
            }
            __syncthreads();

            // ---- controller (replicated; identical in every thread)
            const float en0 = sqrtf(s_err[0] * (1.0f / DATA));
            const float en1 = sqrtf(s_err[1] * (1.0f / DATA));
            const bool acc0 = en0 <= 1.0f, acc1 = en1 <= 1.0f;
            float f0 = fminf(fmaxf(SAFETYc * powf(fmaxf(en0, 1e-10f), -0.2f), FMINc), FMAXc);
            float f1 = fminf(fmaxf(SAFETYc * powf(fmaxf(en1, 1e-10f), -0.2f), FMINc), FMAXc);
            const bool step0 = acc0 && !done0, step1 = acc1 && !done1;
            if (t < 128) {
                const int s = t >> 6;
                const bool st = (s == 0) ? step0 : step1;
                if (st) s_y[s][d] = s_ynew[s][d];
            }
            if (step0) tc0 += dtc0;
            if (step1) tc1 += dtc1;
            dtv0 = done0 ? dtv0 : dtc0 * f0;
            dtv1 = done1 ? dtv1 : dtc1 * f1;
            __syncthreads();
        }

        if (t < 128) {
            const int s = t >> 6;
            out[(size_t)(b * NSAMP + s) * TPTS * DATA + (size_t)(iv + 1) * DATA + d] = s_y[s][d];
        }
        // no barrier needed: next substep reads s_y only after its own barriers
    }
}

extern "C" void kernel_launch(void* const* d_in, const int* in_sizes, int n_in,
                              void* d_out, int out_size, void* d_ws, size_t ws_size,
                              hipStream_t stream)
{
    const float* ts = (const float*)d_in[0];
    const float* y0 = (const float*)d_in[1];
    const float* W0 = (const float*)d_in[2];
    const float* b0 = (const float*)d_in[3];
    const float* W1 = (const float*)d_in[4];
    const float* b1 = (const float*)d_in[5];
    const float* W2 = (const float*)d_in[6];
    const float* b2 = (const float*)d_in[7];
    float* out = (float*)d_out;

    ode_kernel<<<NBLK, NTHR, 0, stream>>>(ts, y0, W0, b0, W1, b1, W2, b2, out);
}